// Round 5
// baseline (608.077 us; speedup 1.0000x reference)
//
#include <hip/hip_runtime.h>
#include <hip/hip_bf16.h>
#include <stdint.h>

// ---------------------------------------------------------------------------
// DQN hypergraph pipeline, round 5: occupancy + pipelining.
//   - split-K doubled (runtime S: SA=16/SB=8 when ws allows, else 8/4)
//     -> 512 blocks/big-gemm = 2 blocks/CU
//   - B operand (T / M activations) pre-split to bf16 hi/lo by producers
//     (small_gemm / reduce_A) -> big_gemm inner loop has no split VALU
//   - register-prefetch double buffer in big_gemm K-loop
// Math identical to round 4 (passed, absmax 5.2e5): A=H plain bf16,
// B activations hi+lo (2 MFMA), small gemms 3-product hi/lo.
// ---------------------------------------------------------------------------

typedef short short8 __attribute__((ext_vector_type(8)));
typedef float f32x4 __attribute__((ext_vector_type(4)));

static constexpr int N = 8192, E = 4096;

__device__ __forceinline__ unsigned rotl32(unsigned x, int r) {
  return (x << r) | (x >> (32 - r));
}

__device__ __forceinline__ uint2 threefry2x32(unsigned k0, unsigned k1,
                                              unsigned x0, unsigned x1) {
  unsigned ks[3] = {k0, k1, k0 ^ k1 ^ 0x1BD11BDAu};
  x0 += ks[0];
  x1 += ks[1];
  const int R0[4] = {13, 15, 26, 6};
  const int R1[4] = {17, 29, 16, 24};
#pragma unroll
  for (int i = 0; i < 5; ++i) {
#pragma unroll
    for (int j = 0; j < 4; ++j) {
      const int r = (i % 2 == 0) ? R0[j] : R1[j];
      x0 += x1;
      x1 = rotl32(x1, r);
      x1 ^= x0;
    }
    x0 += ks[(i + 1) % 3];
    x1 += ks[(i + 2) % 3] + (unsigned)(i + 1);
  }
  return make_uint2(x0, x1);
}

// jax partitionable threefry bernoulli: bits = out.x ^ out.y, keep <=> MSB==0
__device__ __forceinline__ float drop_scale(unsigned idx) {
  const uint2 o = threefry2x32(0u, 42u, 0u, idx);
  return ((o.x ^ o.y) & 0x80000000u) ? 0.0f : 2.0f;
}

__device__ __forceinline__ float lrelu(float v) {
  return v >= 0.0f ? v : 0.01f * v;
}

__device__ __forceinline__ unsigned rne1(float a) {  // f32 -> bf16 bits
  unsigned ua = __builtin_bit_cast(unsigned, a);
  ua += 0x7fffu + ((ua >> 16) & 1u);
  return ua >> 16;
}
__device__ __forceinline__ float bf16_val(unsigned u16) {
  return __builtin_bit_cast(float, u16 << 16);
}
__device__ __forceinline__ unsigned pk_bf16(float a, float b) {
  return rne1(a) | (rne1(b) << 16);
}
__device__ __forceinline__ void split2(float a, float b, unsigned& hi,
                                       unsigned& lo) {
  const unsigned ha = rne1(a), hb = rne1(b);
  const float ra = a - bf16_val(ha), rb = b - bf16_val(hb);
  hi = ha | (hb << 16);
  lo = rne1(ra) | (rne1(rb) << 16);
}
__device__ __forceinline__ void split1(float a, unsigned& hi, unsigned& lo) {
  const unsigned ha = rne1(a);
  hi = ha;
  lo = rne1(a - bf16_val(ha));
}

// ---------------------------------------------------------------------------
// Big split-K GEMM, 128x128 tiles, BK=32, partials P[s][m][c] fp32.
// TRANSA=0: A fp32 [M][K] (Hs), lda=K. TRANSA=1: A fp32 [K][M] (Ht), lda=N.
// Bth/Btl bf16 [128][K] k-contiguous (pre-split hi/lo).
// Register-prefetch double buffer over the K loop.
// ---------------------------------------------------------------------------
template <bool TRANSA>
__global__ __launch_bounds__(256) void big_gemm(
    const float* __restrict__ A, const short* __restrict__ Bth,
    const short* __restrict__ Btl, float* __restrict__ P, int M, int K,
    int lda, int kchunk) {
  __shared__ __align__(16) short As[128 * 40];
  __shared__ __align__(16) short Bhs[128 * 40];
  __shared__ __align__(16) short Bls[128 * 40];

  const int tid = threadIdx.x;
  const int lane = tid & 63;
  const int w = tid >> 6;
  const int wm = (w & 1) << 6;
  const int wn = (w >> 1) << 6;
  const int l15 = lane & 15;
  const int koff = (lane >> 4) << 3;  // shorts

  const int r0 = blockIdx.x * 128;
  const int s = blockIdx.y;
  const int kbeg = s * kchunk;
  const int kend = kbeg + kchunk;

  f32x4 acc[4][4];
#pragma unroll
  for (int i = 0; i < 4; ++i)
#pragma unroll
    for (int j = 0; j < 4; ++j) acc[i][j] = (f32x4){0.f, 0.f, 0.f, 0.f};

  // prefetch registers
  float4 pa[4];     // TRANSA=0
  float pav[2][8];  // TRANSA=1
  uint4 pbh[2], pbl[2];

  auto loadA = [&](int k0) {
    if (!TRANSA) {
#pragma unroll
      for (int i = 0; i < 4; ++i) {
        const int f = i * 256 + tid;  // 0..1023
        const int m = f >> 3;
        const int kq = f & 7;
        pa[i] = *(const float4*)(A + (size_t)(r0 + m) * lda + k0 + 4 * kq);
      }
    } else {
#pragma unroll
      for (int i = 0; i < 2; ++i) {
        const int f = i * 256 + tid;  // 0..511
        const int m = f & 127;
        const int eo = f >> 7;  // 0..3
#pragma unroll
        for (int r = 0; r < 8; ++r)
          pav[i][r] = A[(size_t)(k0 + 8 * eo + r) * lda + (r0 + m)];
      }
    }
  };
  auto loadB = [&](int k0) {
#pragma unroll
    for (int i = 0; i < 2; ++i) {
      const int q = i * 256 + tid;  // 0..511
      const int c = q >> 2;
      const int kqo = q & 3;
      pbh[i] = *(const uint4*)(Bth + (size_t)c * K + k0 + 8 * kqo);
      pbl[i] = *(const uint4*)(Btl + (size_t)c * K + k0 + 8 * kqo);
    }
  };
  auto storeLDS = [&]() {
    if (!TRANSA) {
#pragma unroll
      for (int i = 0; i < 4; ++i) {
        const int f = i * 256 + tid;
        const int m = f >> 3;
        const int kq = f & 7;
        uint2 u = {pk_bf16(pa[i].x, pa[i].y), pk_bf16(pa[i].z, pa[i].w)};
        *(uint2*)&As[m * 40 + 4 * kq] = u;
      }
    } else {
#pragma unroll
      for (int i = 0; i < 2; ++i) {
        const int f = i * 256 + tid;
        const int m = f & 127;
        const int eo = f >> 7;
        uint4 u = {pk_bf16(pav[i][0], pav[i][1]), pk_bf16(pav[i][2], pav[i][3]),
                   pk_bf16(pav[i][4], pav[i][5]),
                   pk_bf16(pav[i][6], pav[i][7])};
        *(uint4*)&As[m * 40 + 8 * eo] = u;
      }
    }
#pragma unroll
    for (int i = 0; i < 2; ++i) {
      const int q = i * 256 + tid;
      const int c = q >> 2;
      const int kqo = q & 3;
      *(uint4*)&Bhs[c * 40 + 8 * kqo] = pbh[i];
      *(uint4*)&Bls[c * 40 + 8 * kqo] = pbl[i];
    }
  };

  loadA(kbeg);
  loadB(kbeg);
  for (int k0 = kbeg; k0 < kend; k0 += 32) {
    storeLDS();
    __syncthreads();
    if (k0 + 32 < kend) {
      loadA(k0 + 32);
      loadB(k0 + 32);
    }
    short8 af[4], bh[4], bl[4];
#pragma unroll
    for (int i = 0; i < 4; ++i)
      af[i] = *(const short8*)&As[(wm + 16 * i + l15) * 40 + koff];
#pragma unroll
    for (int j = 0; j < 4; ++j) {
      bh[j] = *(const short8*)&Bhs[(wn + 16 * j + l15) * 40 + koff];
      bl[j] = *(const short8*)&Bls[(wn + 16 * j + l15) * 40 + koff];
    }
#pragma unroll
    for (int i = 0; i < 4; ++i)
#pragma unroll
      for (int j = 0; j < 4; ++j) {
        acc[i][j] = __builtin_amdgcn_mfma_f32_16x16x32_bf16(af[i], bl[j],
                                                            acc[i][j], 0, 0, 0);
        acc[i][j] = __builtin_amdgcn_mfma_f32_16x16x32_bf16(af[i], bh[j],
                                                            acc[i][j], 0, 0, 0);
      }
    __syncthreads();
  }

  const int rquad = (lane >> 4) << 2;
#pragma unroll
  for (int i = 0; i < 4; ++i)
#pragma unroll
    for (int j = 0; j < 4; ++j)
#pragma unroll
      for (int r = 0; r < 4; ++r) {
        const int row = r0 + wm + 16 * i + rquad + r;
        const int col = wn + 16 * j + l15;
        P[((size_t)s * M + row) * 128 + col] = acc[i][j][r];
      }
}

// ---------------------------------------------------------------------------
// Small GEMM vs 128x128 weight, K=128, both operands hi/lo (3 products).
// WA=1: writes (src@W)^T as bf16 hi/lo pair  [128][N] k-contiguous.
// WA=0: writes src@W as fp32 [n][128] (Badd).
// ---------------------------------------------------------------------------
template <bool WA>
__global__ __launch_bounds__(256) void small_gemm(
    const float* __restrict__ src, const float* __restrict__ W,
    short* __restrict__ outh, short* __restrict__ outl,
    float* __restrict__ outf) {
  __shared__ __align__(16) short WTh[128 * 40], WTl[128 * 40];
  __shared__ __align__(16) short Xh[64 * 40], Xl[64 * 40];

  const int tid = threadIdx.x;
  const int lane = tid & 63;
  const int w = tid >> 6;
  const int l15 = lane & 15;
  const int n0 = blockIdx.x * 64;

  constexpr int TI = WA ? 4 : 2;
  constexpr int TJ = WA ? 2 : 4;
  const int wm = (w & 1) * (WA ? 64 : 32);
  const int wn = (w >> 1) * (WA ? 32 : 64);

  f32x4 acc[TI][TJ];
#pragma unroll
  for (int i = 0; i < TI; ++i)
#pragma unroll
    for (int j = 0; j < TJ; ++j) acc[i][j] = (f32x4){0.f, 0.f, 0.f, 0.f};

  for (int k0 = 0; k0 < 128; k0 += 32) {
    // stage W chunk transposed: WT[c][k] = W[k0+k][c], hi/lo
#pragma unroll
    for (int i = 0; i < 2; ++i) {
      const int f = i * 256 + tid;  // 0..511
      const int c = f & 127;
      const int eo = f >> 7;  // 0..3
      uint4 uh, ul;
      unsigned* ph = (unsigned*)&uh;
      unsigned* pl = (unsigned*)&ul;
#pragma unroll
      for (int r = 0; r < 4; ++r) {
        const float a = W[(size_t)(k0 + 8 * eo + 2 * r) * 128 + c];
        const float b = W[(size_t)(k0 + 8 * eo + 2 * r + 1) * 128 + c];
        split2(a, b, ph[r], pl[r]);
      }
      *(uint4*)&WTh[c * 40 + 8 * eo] = uh;
      *(uint4*)&WTl[c * 40 + 8 * eo] = ul;
    }
    // stage src chunk: X[n][k], hi/lo
#pragma unroll
    for (int i = 0; i < 2; ++i) {
      const int q = i * 256 + tid;  // 0..511
      const int n = q >> 3;         // 0..63
      const int kq = q & 7;
      const float4 v =
          *(const float4*)(src + (size_t)(n0 + n) * 128 + k0 + 4 * kq);
      uint2 uh, ul;
      split2(v.x, v.y, uh.x, ul.x);
      split2(v.z, v.w, uh.y, ul.y);
      *(uint2*)&Xh[n * 40 + 4 * kq] = uh;
      *(uint2*)&Xl[n * 40 + 4 * kq] = ul;
    }
    __syncthreads();

    const int koff = (lane >> 4) << 3;
    short8 ah[TI], al[TI], bh[TJ], bl[TJ];
#pragma unroll
    for (int i = 0; i < TI; ++i) {
      const int m = wm + 16 * i + l15;
      ah[i] = WA ? *(const short8*)&WTh[m * 40 + koff]
                 : *(const short8*)&Xh[m * 40 + koff];
      al[i] = WA ? *(const short8*)&WTl[m * 40 + koff]
                 : *(const short8*)&Xl[m * 40 + koff];
    }
#pragma unroll
    for (int j = 0; j < TJ; ++j) {
      const int c = wn + 16 * j + l15;
      bh[j] = WA ? *(const short8*)&Xh[c * 40 + koff]
                 : *(const short8*)&WTh[c * 40 + koff];
      bl[j] = WA ? *(const short8*)&Xl[c * 40 + koff]
                 : *(const short8*)&WTl[c * 40 + koff];
    }
#pragma unroll
    for (int i = 0; i < TI; ++i)
#pragma unroll
      for (int j = 0; j < TJ; ++j) {
        acc[i][j] = __builtin_amdgcn_mfma_f32_16x16x32_bf16(al[i], bh[j],
                                                            acc[i][j], 0, 0, 0);
        acc[i][j] = __builtin_amdgcn_mfma_f32_16x16x32_bf16(ah[i], bl[j],
                                                            acc[i][j], 0, 0, 0);
        acc[i][j] = __builtin_amdgcn_mfma_f32_16x16x32_bf16(ah[i], bh[j],
                                                            acc[i][j], 0, 0, 0);
      }
    __syncthreads();
  }

  const int rquad = (lane >> 4) << 2;
#pragma unroll
  for (int i = 0; i < TI; ++i)
#pragma unroll
    for (int j = 0; j < TJ; ++j)
#pragma unroll
      for (int r = 0; r < 4; ++r) {
        const int row = wm + 16 * i + rquad + r;
        const int col = wn + 16 * j + l15;
        const float v = acc[i][j][r];
        if (WA) {  // T^T hi/lo: [c][N]
          unsigned hi, lo;
          split1(v, hi, lo);
          outh[(size_t)row * N + n0 + col] = (short)hi;
          outl[(size_t)row * N + n0 + col] = (short)lo;
        } else {  // Badd fp32 [n][128]
          outf[(size_t)(n0 + row) * 128 + col] = v;
        }
      }
}

// Mth/Mtl[c][e] = hi/lo of ew[e] * sum_s P[s][e][c];  P [S][E][128]
__global__ __launch_bounds__(256) void reduce_A(const float* __restrict__ P,
                                                const float* __restrict__ ew,
                                                short* __restrict__ Mth,
                                                short* __restrict__ Mtl,
                                                int S) {
  __shared__ float Lt[32 * 132];
  const int tid = threadIdx.x;
  const int e0 = blockIdx.x * 32;
#pragma unroll
  for (int i = 0; i < 4; ++i) {
    const int f = i * 256 + tid;  // 0..1023
    const int el = f >> 5;
    const int cq = f & 31;
    float4 a = {0.f, 0.f, 0.f, 0.f};
    for (int s = 0; s < S; ++s) {
      const float4 v =
          *(const float4*)(P + ((size_t)s * E + e0 + el) * 128 + 4 * cq);
      a.x += v.x; a.y += v.y; a.z += v.z; a.w += v.w;
    }
    const float sc = ew[e0 + el];
    a.x *= sc; a.y *= sc; a.z *= sc; a.w *= sc;
    *(float4*)&Lt[el * 132 + 4 * cq] = a;
  }
  __syncthreads();
#pragma unroll
  for (int i = 0; i < 4; ++i) {
    const int g = i * 256 + tid;  // 0..1023
    const int c = g >> 3;
    const int eq = g & 7;
    float o0 = Lt[(4 * eq + 0) * 132 + c];
    float o1 = Lt[(4 * eq + 1) * 132 + c];
    float o2 = Lt[(4 * eq + 2) * 132 + c];
    float o3 = Lt[(4 * eq + 3) * 132 + c];
    uint2 uh, ul;
    split2(o0, o1, uh.x, ul.x);
    split2(o2, o3, uh.y, ul.y);
    *(uint2*)&Mth[(size_t)c * E + e0 + 4 * eq] = uh;
    *(uint2*)&Mtl[(size_t)c * E + e0 + 4 * eq] = ul;
  }
}

// X1[n][c] = dropout(lrelu(sum_s P + Badd + bias));  P [S][N][128]
__global__ __launch_bounds__(256) void reduce_B1(const float* __restrict__ P,
                                                 const float* __restrict__ Badd,
                                                 const float* __restrict__ bias,
                                                 float* __restrict__ X1,
                                                 int S) {
  const int q = blockIdx.x * 256 + threadIdx.x;
  const int n = q >> 5;
  const int cq = q & 31;
  float4 a = {0.f, 0.f, 0.f, 0.f};
  for (int s = 0; s < S; ++s) {
    const float4 v = *(const float4*)(P + ((size_t)s * N + n) * 128 + 4 * cq);
    a.x += v.x; a.y += v.y; a.z += v.z; a.w += v.w;
  }
  const float4 b = *(const float4*)(Badd + (size_t)n * 128 + 4 * cq);
  const float4 bi = *(const float4*)(bias + 4 * cq);
  const unsigned fb = (unsigned)(n * 128 + 4 * cq);
  float4 o;
  o.x = lrelu(a.x + b.x + bi.x) * drop_scale(fb + 0u);
  o.y = lrelu(a.y + b.y + bi.y) * drop_scale(fb + 1u);
  o.z = lrelu(a.z + b.z + bi.z) * drop_scale(fb + 2u);
  o.w = lrelu(a.w + b.w + bi.w) * drop_scale(fb + 3u);
  *(float4*)&X1[(size_t)n * 128 + 4 * cq] = o;
}

// out[n] = sum_c lrelu(lrelu(sum_s P + Badd + bias)) * fcw[c]
//          + state[n]*fcw[128] + fcb[0]
__global__ __launch_bounds__(256) void reduce_B2(
    const float* __restrict__ P, const float* __restrict__ Badd,
    const float* __restrict__ bias, const float* __restrict__ fcw,
    const float* __restrict__ state, const float* __restrict__ fcb,
    float* __restrict__ out, int S) {
  __shared__ float part[4];
  const int tid = threadIdx.x;
  const int nn = tid >> 7;
  const int c = tid & 127;
  const int n = blockIdx.x * 2 + nn;
  float v = 0.f;
  for (int s = 0; s < S; ++s) v += P[((size_t)s * N + n) * 128 + c];
  v += Badd[(size_t)n * 128 + c] + bias[c];
  float p = lrelu(lrelu(v)) * fcw[c];
#pragma unroll
  for (int m = 32; m >= 1; m >>= 1) p += __shfl_xor(p, m, 64);
  if ((tid & 63) == 0) part[tid >> 6] = p;
  __syncthreads();
  if (tid < 2)
    out[blockIdx.x * 2 + tid] = part[2 * tid] + part[2 * tid + 1] +
                                state[blockIdx.x * 2 + tid] * fcw[128] + fcb[0];
}

extern "C" void kernel_launch(void* const* d_in, const int* in_sizes, int n_in,
                              void* d_out, int out_size, void* d_ws,
                              size_t ws_size, hipStream_t stream) {
  (void)in_sizes; (void)n_in; (void)out_size;

  const float* xi = (const float*)d_in[0];
  const float* x = (const float*)d_in[1];
  const float* Ht = (const float*)d_in[2];   // [E][N]
  const float* Hs = (const float*)d_in[3];   // [E][N]
  const float* state = (const float*)d_in[4];
  const float* wt0 = (const float*)d_in[5];
  const float* th0 = (const float*)d_in[6];
  const float* ew0 = (const float*)d_in[7];
  const float* bi0 = (const float*)d_in[8];
  const float* wt1 = (const float*)d_in[9];
  const float* th1 = (const float*)d_in[10];
  const float* ew1 = (const float*)d_in[11];
  const float* bi1 = (const float*)d_in[12];
  const float* fcw = (const float*)d_in[13];  // [129]
  const float* fcb = (const float*)d_in[14];  // [1]
  float* out = (float*)d_out;                 // [8192]

  // split-K: prefer SA=16/SB=8 (512 blocks = 2 blocks/CU); needs ~47.5MB ws.
  const bool big_ws = ws_size >= ((size_t)48 << 20);
  const int SAe = big_ws ? 16 : 8;
  const int SBe = big_ws ? 8 : 4;
  const size_t Pfloats = (size_t)SAe * E * 128;  // == SBe*N*128

  // ws layout: P fp32 | Tth | Ttl (bf16 [128][N]) | Mth | Mtl (bf16 [128][E])
  //            | Badd fp32 [N][128] | X1 fp32 [N][128]
  char* wsb = (char*)d_ws;
  float* P = (float*)wsb;
  short* Tth = (short*)(wsb + Pfloats * 4);
  short* Ttl = Tth + (size_t)128 * N;
  short* Mth = Ttl + (size_t)128 * N;
  short* Mtl = Mth + (size_t)128 * E;
  float* Badd = (float*)(Mtl + (size_t)128 * E);
  float* X1 = Badd + (size_t)N * 128;

  const dim3 blk(256);

  // ---- layer 1 ----
  small_gemm<true><<<N / 64, blk, 0, stream>>>(x, th0, Tth, Ttl, nullptr);
  small_gemm<false><<<N / 64, blk, 0, stream>>>(xi, wt0, nullptr, nullptr,
                                                Badd);
  big_gemm<false><<<dim3(E / 128, SAe), blk, 0, stream>>>(Hs, Tth, Ttl, P, E,
                                                          N, N, N / SAe);
  reduce_A<<<E / 32, blk, 0, stream>>>(P, ew0, Mth, Mtl, SAe);
  big_gemm<true><<<dim3(N / 128, SBe), blk, 0, stream>>>(Ht, Mth, Mtl, P, N,
                                                         E, N, E / SBe);
  reduce_B1<<<N * 128 / 4 / 256, blk, 0, stream>>>(P, Badd, bi0, X1, SBe);

  // ---- layer 2 + head ----
  small_gemm<true><<<N / 64, blk, 0, stream>>>(X1, th1, Tth, Ttl, nullptr);
  small_gemm<false><<<N / 64, blk, 0, stream>>>(xi, wt1, nullptr, nullptr,
                                                Badd);
  big_gemm<false><<<dim3(E / 128, SAe), blk, 0, stream>>>(Hs, Tth, Ttl, P, E,
                                                          N, N, N / SAe);
  reduce_A<<<E / 32, blk, 0, stream>>>(P, ew1, Mth, Mtl, SAe);
  big_gemm<true><<<dim3(N / 128, SBe), blk, 0, stream>>>(Ht, Mth, Mtl, P, N,
                                                         E, N, E / SBe);
  reduce_B2<<<N / 2, blk, 0, stream>>>(P, Badd, bi1, fcw, state, fcb, out,
                                       SBe);
}